// Round 8
// baseline (590.047 us; speedup 1.0000x reference)
//
#include <hip/hip_runtime.h>
#include <math.h>

// Problem constants
#define BB   32
#define SS   512
#define EE   256
#define HH   8
#define LL   4
#define FFD  1024
#define DHD  32
#define FCH  128     // FFD chunk in k_ffn

constexpr float LN_EPS = 1e-5f;
constexpr int   NBSE   = BB * SS * EE;   // 4,194,304

typedef float  f32x4  __attribute__((ext_vector_type(4)));
typedef __bf16 bf16;
typedef __bf16 bf16x4 __attribute__((ext_vector_type(4)));
typedef __bf16 bf16x8 __attribute__((ext_vector_type(8)));

// tanh-form GELU (|err| vs exact erf-GELU ~1e-3, safe within bf16 tolerance)
__device__ __forceinline__ float gelu_f(float x) {
    float u = x * x;
    float t = 1.5957691216057308f * x * (1.0f + 0.044715f * u);
    return x / (1.0f + __expf(-t));
}

// ---------------------------------------------------------------- weight prep
// weight transpose+convert: in [K][N] f32 -> out [N][K] bf16, layer = blockIdx.z
__global__ __launch_bounds__(256) void k_cvt_t(const float* __restrict__ in,
                                               bf16* __restrict__ out,
                                               int K, int N) {
    __shared__ float tile[32][33];
    in  += (size_t)blockIdx.z * K * N;
    out += (size_t)blockIdx.z * K * N;
    int n0 = blockIdx.x * 32, k0 = blockIdx.y * 32;
    int tx = threadIdx.x & 31, ty = threadIdx.x >> 5;   // 32 x 8
    #pragma unroll
    for (int i = 0; i < 32; i += 8)
        tile[ty + i][tx] = in[(size_t)(k0 + ty + i) * N + n0 + tx];
    __syncthreads();
    #pragma unroll
    for (int i = 0; i < 32; i += 8)
        out[(size_t)(n0 + ty + i) * K + k0 + tx] = (bf16)tile[tx][ty + i];
}

// QKV weight transpose: W[l][h][d][e] f32 -> Wt[l][h][e][d] bf16 (q scaled by 1/sqrt(DH))
__global__ __launch_bounds__(256) void k_cvt_qkv(const float* __restrict__ Wq,
                                                 const float* __restrict__ Wk,
                                                 const float* __restrict__ Wv,
                                                 bf16* __restrict__ Wqt,
                                                 bf16* __restrict__ Wkt,
                                                 bf16* __restrict__ Wvt) {
    __shared__ float tile[32][33];
    int lh = blockIdx.x;            // l*H + h
    int z  = blockIdx.y;            // 0=q,1=k,2=v
    const float* in = (z == 0 ? Wq : z == 1 ? Wk : Wv) + (size_t)lh * 1024;
    bf16* out       = (z == 0 ? Wqt : z == 1 ? Wkt : Wvt) + (size_t)lh * 1024;
    float scale = (z == 0) ? 0.17677669529663687f : 1.0f;
    int tx = threadIdx.x & 31, ty = threadIdx.x >> 5;
    #pragma unroll
    for (int i = 0; i < 32; i += 8)
        tile[ty + i][tx] = in[(ty + i) * 32 + tx];
    __syncthreads();
    #pragma unroll
    for (int i = 0; i < 32; i += 8)
        out[(ty + i) * 32 + tx] = (bf16)(tile[tx][ty + i] * scale);
}

// ---------------------------------------------------------------- fused (addpos+)LN+QKV (MFMA)
// grid (B, S/64); 4 waves, wave w owns 16 s-rows. Outputs q,k [bh][s][d], v [bh][d][s].
template <bool ADDPOS>
__global__ __launch_bounds__(256) void k_lnqkv(const float* __restrict__ xin,
                                               const float* __restrict__ pos,
                                               float* __restrict__ hout,
                                               const bf16* __restrict__ Wqt,
                                               const bf16* __restrict__ Wkt,
                                               const bf16* __restrict__ Wvt,
                                               bf16* __restrict__ qb,
                                               bf16* __restrict__ kb,
                                               bf16* __restrict__ vb) {
    __shared__ __attribute__((aligned(16))) bf16 Xs[64 * 264];
    int b = blockIdx.x, s0 = blockIdx.y * 64;
    int tid = threadIdx.x, w = tid >> 6, lane = tid & 63;
    size_t rowoff = ((size_t)(b * SS + s0 + w * 16)) * EE + lane * 4;
    const float* hb = xin + rowoff;
    float4 pv;
    if (ADDPOS) pv = *(const float4*)(pos + lane * 4);
    float4 xr[16];
    #pragma unroll
    for (int i = 0; i < 16; i++)
        xr[i] = *(const float4*)(hb + (size_t)i * EE);
    if (ADDPOS) {
        #pragma unroll
        for (int i = 0; i < 16; i++) {
            xr[i].x += pv.x; xr[i].y += pv.y; xr[i].z += pv.z; xr[i].w += pv.w;
            *(float4*)(hout + rowoff + (size_t)i * EE) = xr[i];
        }
    }
    #pragma unroll
    for (int i = 0; i < 16; i++) {
        float4 v4 = xr[i];
        float sum = v4.x + v4.y + v4.z + v4.w;
        #pragma unroll
        for (int m = 1; m <= 32; m <<= 1) sum += __shfl_xor(sum, m, 64);
        float mean = sum * (1.0f / EE);
        float dx = v4.x - mean, dy = v4.y - mean, dz = v4.z - mean, dw = v4.w - mean;
        float ss = dx * dx + dy * dy + dz * dz + dw * dw;
        #pragma unroll
        for (int m = 1; m <= 32; m <<= 1) ss += __shfl_xor(ss, m, 64);
        float rstd = rsqrtf(ss * (1.0f / EE) + LN_EPS);
        bf16x4 o4 = { (bf16)(dx * rstd), (bf16)(dy * rstd), (bf16)(dz * rstd), (bf16)(dw * rstd) };
        *(bf16x4*)&Xs[(w * 16 + i) * 264 + lane * 4] = o4;
    }
    __syncthreads();
    int col = lane & 15, quad = lane >> 4;
    #pragma unroll
    for (int h = 0; h < HH; h++) {
        bf16x8 a = *(const bf16x8*)&Xs[(w * 16 + col) * 264 + h * 32 + quad * 8];
        size_t base = ((size_t)((b * HH + h) * SS) + s0 + w * 16) * DHD;
        #pragma unroll
        for (int nt = 0; nt < 2; nt++) {
            int e = nt * 16 + col;
            bf16x8 bq  = *(const bf16x8*)(Wqt + (h * 32 + e) * 32 + quad * 8);
            bf16x8 bk2 = *(const bf16x8*)(Wkt + (h * 32 + e) * 32 + quad * 8);
            bf16x8 bv2 = *(const bf16x8*)(Wvt + (h * 32 + e) * 32 + quad * 8);
            f32x4 z = {0.f, 0.f, 0.f, 0.f};
            f32x4 cq = __builtin_amdgcn_mfma_f32_16x16x32_bf16(a, bq, z, 0, 0, 0);
            f32x4 ck = __builtin_amdgcn_mfma_f32_16x16x32_bf16(a, bk2, z, 0, 0, 0);
            f32x4 cv = __builtin_amdgcn_mfma_f32_16x16x32_bf16(a, bv2, z, 0, 0, 0);
            #pragma unroll
            for (int r = 0; r < 4; r++) {
                qb[base + (quad * 4 + r) * DHD + e] = (bf16)cq[r];
                kb[base + (quad * 4 + r) * DHD + e] = (bf16)ck[r];
            }
            bf16x4 vv = { (bf16)cv[0], (bf16)cv[1], (bf16)cv[2], (bf16)cv[3] };
            *(bf16x4*)&vb[(((size_t)(b * HH + h)) * DHD + e) * SS + s0 + w * 16 + quad * 4] = vv;
        }
    }
}

// ---------------------------------------------------------------- MFMA flash attention v3
// S^T formulation, fixed-max softmax, 128-q tile; O bf16 concat layout [b][s][E].
#define ATT_LDK 40
#define ATT_LDV 264
#define ATT_LDP 36
__global__ __launch_bounds__(256) void k_attn(const bf16* __restrict__ Q,
                                              const bf16* __restrict__ K,
                                              const bf16* __restrict__ VT,
                                              bf16* __restrict__ O) {
    __shared__ __attribute__((aligned(16))) bf16 Ks[256 * ATT_LDK];
    __shared__ __attribute__((aligned(16))) bf16 Vs[32 * ATT_LDV];
    __shared__ __attribute__((aligned(16))) bf16 Ps[4][16 * ATT_LDP];
    int bh = blockIdx.x;
    int q0 = blockIdx.y * 128;
    int tid = threadIdx.x;
    int w = tid >> 6, lane = tid & 63;
    int col = lane & 15, quad = lane >> 4;
    bf16x8 aq[2];
    #pragma unroll
    for (int sub = 0; sub < 2; sub++)
        aq[sub] = *(const bf16x8*)(Q + ((size_t)(bh * SS + q0 + sub * 64 + w * 16 + col)) * DHD + quad * 8);
    float lr[2] = {0.f, 0.f};
    f32x4 oacc[2][2] = {};
    int ksr = tid >> 2, ksc = (tid & 3) * 8;   // K staging: 64 rows/iter x 32 d
    int vd  = tid >> 5, vso = (tid & 31) * 8;  // VT staging: 8 d-rows/pass x 256 s
    for (int ph = 0; ph < 2; ph++) {
        int t00 = ph * 256;
        __syncthreads();
        #pragma unroll
        for (int it = 0; it < 4; it++) {
            int rl = it * 64 + ksr;
            *(bf16x8*)&Ks[rl * ATT_LDK + ksc] =
                *(const bf16x8*)(K + ((size_t)(bh * SS + t00 + rl)) * DHD + ksc);
        }
        #pragma unroll
        for (int it = 0; it < 4; it++) {
            int d = it * 8 + vd;
            *(bf16x8*)&Vs[d * ATT_LDV + vso] =
                *(const bf16x8*)(VT + (((size_t)bh * DHD + d) * SS) + t00 + vso);
        }
        __syncthreads();
        #pragma unroll
        for (int i = 0; i < 8; i++) {
            bf16x8 bk[2], bv[2];
            #pragma unroll
            for (int nt = 0; nt < 2; nt++) {
                bk[nt] = *(const bf16x8*)&Ks[(i * 32 + nt * 16 + col) * ATT_LDK + quad * 8];
                bv[nt] = *(const bf16x8*)&Vs[(nt * 16 + col) * ATT_LDV + i * 32 + quad * 8];
            }
            #pragma unroll
            for (int sub = 0; sub < 2; sub++) {
                #pragma unroll
                for (int nt = 0; nt < 2; nt++) {
                    f32x4 z = {0.f, 0.f, 0.f, 0.f};
                    f32x4 st = __builtin_amdgcn_mfma_f32_16x16x32_bf16(bk[nt], aq[sub], z, 0, 0, 0);
                    bf16x4 p4;
                    #pragma unroll
                    for (int r = 0; r < 4; r++) {
                        float p = __expf(st[r]);
                        lr[sub] += p;
                        p4[r] = (bf16)p;
                    }
                    *(bf16x4*)&Ps[w][col * ATT_LDP + nt * 16 + quad * 4] = p4;
                }
                bf16x4 apl = *(const bf16x4*)&Ps[w][col * ATT_LDP + quad * 8];
                bf16x4 aph = *(const bf16x4*)&Ps[w][col * ATT_LDP + quad * 8 + 4];
                bf16x8 ap;
                ap[0] = apl[0]; ap[1] = apl[1]; ap[2] = apl[2]; ap[3] = apl[3];
                ap[4] = aph[0]; ap[5] = aph[1]; ap[6] = aph[2]; ap[7] = aph[3];
                #pragma unroll
                for (int nt = 0; nt < 2; nt++)
                    oacc[sub][nt] = __builtin_amdgcn_mfma_f32_16x16x32_bf16(ap, bv[nt], oacc[sub][nt], 0, 0, 0);
            }
        }
    }
    int b = bh >> 3, hh = bh & 7;
    #pragma unroll
    for (int sub = 0; sub < 2; sub++) {
        float ls = lr[sub];
        ls += __shfl_xor(ls, 16, 64);
        ls += __shfl_xor(ls, 32, 64);
        #pragma unroll
        for (int r = 0; r < 4; r++) {
            float lrow = __shfl(ls, quad * 4 + r, 64);
            float inv = 1.0f / lrow;
            int row = q0 + sub * 64 + w * 16 + quad * 4 + r;
            size_t ob = ((size_t)(b * SS + row)) * EE + hh * 32;
            O[ob + col]      = (bf16)(oacc[sub][0][r] * inv);
            O[ob + 16 + col] = (bf16)(oacc[sub][1][r] * inv);
        }
    }
}

// ---------------------------------------------------------------- fused FFN
// per block: 64 rows. res=ob+h -> LN -> A (LDS, A-frags hoisted to regs) ->
// per 128-wide FFD chunk: P = gelu(A@W1+b1) (W1 frags direct from global/L2) ->
// accF += P@W2 (W2 direct from global/L2) -> out = accF + b2 + res.
// 512 threads (8 waves): wave w -> rows (w>>2)*32..+31, gemm1 cols (w&3)*32,
// gemm2 out-cols (w&3)*64. Barriers only around P (2 per chunk).
__global__ __launch_bounds__(512, 2) void k_ffn(const bf16* __restrict__ ob,
                                                const float* __restrict__ hb,
                                                const bf16* __restrict__ W1t,  // [FFD][E]
                                                const float* __restrict__ b1,
                                                const bf16* __restrict__ W2t,  // [E][FFD]
                                                const float* __restrict__ b2,
                                                float* __restrict__ out) {
    __shared__ __attribute__((aligned(16))) bf16 As[64 * 264];
    __shared__ __attribute__((aligned(16))) bf16 Ps[64 * 136];
    int tid = threadIdx.x, w = tid >> 6, lane = tid & 63;
    int col = lane & 15, quad = lane >> 4;
    int row0 = blockIdx.x * 64;
    // ---- prologue: res + LN -> As (wave w: rows w*8..w*8+7)
    #pragma unroll
    for (int i = 0; i < 8; i++) {
        int r = w * 8 + i;
        float4 h4 = *(const float4*)(hb + (size_t)(row0 + r) * EE + lane * 4);
        bf16x4 o4 = *(const bf16x4*)(ob + (size_t)(row0 + r) * EE + lane * 4);
        float v0 = h4.x + (float)o4[0], v1 = h4.y + (float)o4[1];
        float v2 = h4.z + (float)o4[2], v3 = h4.w + (float)o4[3];
        float sum = v0 + v1 + v2 + v3;
        #pragma unroll
        for (int m = 1; m <= 32; m <<= 1) sum += __shfl_xor(sum, m, 64);
        float mean = sum * (1.0f / EE);
        float d0 = v0 - mean, d1 = v1 - mean, d2 = v2 - mean, d3 = v3 - mean;
        float sq = d0 * d0 + d1 * d1 + d2 * d2 + d3 * d3;
        #pragma unroll
        for (int m = 1; m <= 32; m <<= 1) sq += __shfl_xor(sq, m, 64);
        float rstd = rsqrtf(sq * (1.0f / EE) + LN_EPS);
        bf16x4 a4 = { (bf16)(d0 * rstd), (bf16)(d1 * rstd), (bf16)(d2 * rstd), (bf16)(d3 * rstd) };
        *(bf16x4*)&As[r * 264 + lane * 4] = a4;
    }
    __syncthreads();
    // ---- hoist A-frags: rows mrow+mt*16+col, all 8 k-steps (never re-read)
    int mrow  = (w >> 2) * 32;
    int ncol1 = (w & 3) * 32;    // gemm1 chunk-col base
    int ncol2 = (w & 3) * 64;    // gemm2 out-col base
    bf16x8 af[2][8];
    #pragma unroll
    for (int mt = 0; mt < 2; mt++)
        #pragma unroll
        for (int s = 0; s < 8; s++)
            af[mt][s] = *(const bf16x8*)&As[(mrow + mt * 16 + col) * 264 + s * 32 + quad * 8];
    f32x4 accF[2][4] = {};
    for (int c = 0; c < 8; c++) {
        // ---- gemm1 chunk: accC[mt][nt], W1 frags direct from global (L2-hot)
        f32x4 accC[2][2] = {};
        #pragma unroll
        for (int s = 0; s < 8; s++) {
            #pragma unroll
            for (int nt = 0; nt < 2; nt++) {
                bf16x8 bfv = *(const bf16x8*)(W1t +
                    (size_t)(c * FCH + ncol1 + nt * 16 + col) * EE + s * 32 + quad * 8);
                #pragma unroll
                for (int mt = 0; mt < 2; mt++)
                    accC[mt][nt] = __builtin_amdgcn_mfma_f32_16x16x32_bf16(bfv, af[mt][s], accC[mt][nt], 0, 0, 0);
            }
        }
        // ---- gelu + bias -> P (packed b64 writes; lane holds 4 consecutive chunk-cols)
        #pragma unroll
        for (int mt = 0; mt < 2; mt++)
            #pragma unroll
            for (int nt = 0; nt < 2; nt++) {
                int ccl = ncol1 + nt * 16 + quad * 4;        // chunk-local col
                float4 b4 = *(const float4*)&b1[c * FCH + ccl];
                bf16x4 p4;
                p4[0] = (bf16)gelu_f(accC[mt][nt][0] + b4.x);
                p4[1] = (bf16)gelu_f(accC[mt][nt][1] + b4.y);
                p4[2] = (bf16)gelu_f(accC[mt][nt][2] + b4.z);
                p4[3] = (bf16)gelu_f(accC[mt][nt][3] + b4.w);
                *(bf16x4*)&Ps[(mrow + mt * 16 + col) * 136 + ccl] = p4;
            }
        __syncthreads();
        // ---- gemm2 chunk: accF += P @ W2 (W2 frags direct from global/L2)
        #pragma unroll
        for (int s2 = 0; s2 < 4; s2++) {
            bf16x8 ap[2];
            #pragma unroll
            for (int mt = 0; mt < 2; mt++)
                ap[mt] = *(const bf16x8*)&Ps[(mrow + mt * 16 + col) * 136 + s2 * 32 + quad * 8];
            #pragma unroll
            for (int nt = 0; nt < 4; nt++) {
                bf16x8 bw = *(const bf16x8*)(W2t +
                    (size_t)(ncol2 + nt * 16 + col) * FFD + c * FCH + s2 * 32 + quad * 8);
                #pragma unroll
                for (int mt = 0; mt < 2; mt++)
                    accF[mt][nt] = __builtin_amdgcn_mfma_f32_16x16x32_bf16(bw, ap[mt], accF[mt][nt], 0, 0, 0);
            }
        }
        __syncthreads();   // P consumed; safe to rewrite next chunk
    }
    // ---- epilogue: out = accF + b2 + (ob + h), packed float4 stores
    #pragma unroll
    for (int mt = 0; mt < 2; mt++) {
        int row = row0 + mrow + mt * 16 + col;
        #pragma unroll
        for (int nt = 0; nt < 4; nt++) {
            int cc = ncol2 + nt * 16 + quad * 4;
            float4 b4 = *(const float4*)&b2[cc];
            float4 h4 = *(const float4*)&hb[(size_t)row * EE + cc];
            bf16x4 o4 = *(const bf16x4*)&ob[(size_t)row * EE + cc];
            float4 o;
            o.x = accF[mt][nt][0] + b4.x + h4.x + (float)o4[0];
            o.y = accF[mt][nt][1] + b4.y + h4.y + (float)o4[1];
            o.z = accF[mt][nt][2] + b4.z + h4.z + (float)o4[2];
            o.w = accF[mt][nt][3] + b4.w + h4.w + (float)o4[3];
            *(float4*)&out[(size_t)row * EE + cc] = o;
        }
    }
}

// ---------------------------------------------------------------- launch
extern "C" void kernel_launch(void* const* d_in, const int* in_sizes, int n_in,
                              void* d_out, int out_size, void* d_ws, size_t ws_size,
                              hipStream_t stream) {
    (void)in_sizes; (void)n_in; (void)out_size; (void)ws_size;
    const float* x   = (const float*)d_in[0];
    const float* pos = (const float*)d_in[1];
    const float* Wq  = (const float*)d_in[2];
    const float* Wk  = (const float*)d_in[3];
    const float* Wv  = (const float*)d_in[4];
    const float* W1  = (const float*)d_in[5];
    const float* b1  = (const float*)d_in[6];
    const float* W2  = (const float*)d_in[7];
    const float* b2  = (const float*)d_in[8];

    float* ws = (float*)d_ws;
    size_t N = (size_t)NBSE;
    float* h  = ws;                          // [0 .. 16MB) f32 residual stream
    bf16* ob  = (bf16*)(ws + N);             // [16 .. 24MB) attention out, concat layout
    bf16* qb  = (bf16*)(ws + 2 * N);         // [32 .. 40MB)
    bf16* kb  = qb + N;                      // [40 .. 48MB)
    bf16* vb  = kb + N;                      // [48 .. 56MB) (VT layout [bh][d][s])
    bf16* W1t = (bf16*)(ws + 4 * N);         // [64MB ..)
    bf16* W2t = W1t + (size_t)LL * EE * FFD;
    bf16* Wqt = W2t + (size_t)LL * EE * FFD;
    bf16* Wkt = Wqt + (size_t)LL * HH * DHD * DHD;
    bf16* Wvt = Wkt + (size_t)LL * HH * DHD * DHD;

    k_cvt_t<<<dim3(FFD / 32, EE / 32, LL), 256, 0, stream>>>(W1, W1t, EE, FFD);
    k_cvt_t<<<dim3(EE / 32, FFD / 32, LL), 256, 0, stream>>>(W2, W2t, FFD, EE);
    k_cvt_qkv<<<dim3(LL * HH, 3), 256, 0, stream>>>(Wq, Wk, Wv, Wqt, Wkt, Wvt);
    for (int l = 0; l < LL; l++) {
        if (l == 0)
            k_lnqkv<true><<<dim3(BB, SS / 64), 256, 0, stream>>>(
                x, pos, h, Wqt, Wkt, Wvt, qb, kb, vb);
        else
            k_lnqkv<false><<<dim3(BB, SS / 64), 256, 0, stream>>>(
                h, nullptr, nullptr,
                Wqt + (size_t)l * HH * DHD * DHD, Wkt + (size_t)l * HH * DHD * DHD,
                Wvt + (size_t)l * HH * DHD * DHD, qb, kb, vb);
        k_attn<<<dim3(BB * HH, SS / 128), 256, 0, stream>>>(qb, kb, vb, ob);
        float* outp = (l == LL - 1) ? (float*)d_out : h;
        k_ffn<<<BB * SS / 64, 512, 0, stream>>>(
            ob, h, W1t + (size_t)l * FFD * EE, b1 + (size_t)l * FFD,
            W2t + (size_t)l * EE * FFD, b2 + (size_t)l * EE, outp);
    }
}

// Round 9
// 535.848 us; speedup vs baseline: 1.1011x; 1.1011x over previous
//
#include <hip/hip_runtime.h>
#include <math.h>

// Problem constants
#define BB   32
#define SS   512
#define EE   256
#define HH   8
#define LL   4
#define FFD  1024
#define DHD  32

constexpr float LN_EPS = 1e-5f;
constexpr int   NBSE   = BB * SS * EE;   // 4,194,304

typedef float  f32x4  __attribute__((ext_vector_type(4)));
typedef __bf16 bf16;
typedef __bf16 bf16x4 __attribute__((ext_vector_type(4)));
typedef __bf16 bf16x8 __attribute__((ext_vector_type(8)));

// async global->LDS, 16B per lane; LDS dest is wave-uniform base + lane*16B
__device__ __forceinline__ void glds16(const bf16* g, bf16* l) {
    __builtin_amdgcn_global_load_lds(
        (const __attribute__((address_space(1))) void*)g,
        (__attribute__((address_space(3))) void*)l,
        16, 0, 0);
}

// tanh-form GELU (|err| vs exact erf-GELU ~1e-3, safe within bf16 tolerance)
__device__ __forceinline__ float gelu_f(float x) {
    float u = x * x;
    float t = 1.5957691216057308f * x * (1.0f + 0.044715f * u);
    return x / (1.0f + __expf(-t));
}

// ---------------------------------------------------------------- weight prep
__global__ __launch_bounds__(256) void k_cvt_t(const float* __restrict__ in,
                                               bf16* __restrict__ out,
                                               int K, int N) {
    __shared__ float tile[32][33];
    in  += (size_t)blockIdx.z * K * N;
    out += (size_t)blockIdx.z * K * N;
    int n0 = blockIdx.x * 32, k0 = blockIdx.y * 32;
    int tx = threadIdx.x & 31, ty = threadIdx.x >> 5;   // 32 x 8
    #pragma unroll
    for (int i = 0; i < 32; i += 8)
        tile[ty + i][tx] = in[(size_t)(k0 + ty + i) * N + n0 + tx];
    __syncthreads();
    #pragma unroll
    for (int i = 0; i < 32; i += 8)
        out[(size_t)(n0 + ty + i) * K + k0 + tx] = (bf16)tile[tx][ty + i];
}

__global__ __launch_bounds__(256) void k_cvt_qkv(const float* __restrict__ Wq,
                                                 const float* __restrict__ Wk,
                                                 const float* __restrict__ Wv,
                                                 bf16* __restrict__ Wqt,
                                                 bf16* __restrict__ Wkt,
                                                 bf16* __restrict__ Wvt) {
    __shared__ float tile[32][33];
    int lh = blockIdx.x;            // l*H + h
    int z  = blockIdx.y;            // 0=q,1=k,2=v
    const float* in = (z == 0 ? Wq : z == 1 ? Wk : Wv) + (size_t)lh * 1024;
    bf16* out       = (z == 0 ? Wqt : z == 1 ? Wkt : Wvt) + (size_t)lh * 1024;
    float scale = (z == 0) ? 0.17677669529663687f : 1.0f;
    int tx = threadIdx.x & 31, ty = threadIdx.x >> 5;
    #pragma unroll
    for (int i = 0; i < 32; i += 8)
        tile[ty + i][tx] = in[(ty + i) * 32 + tx];
    __syncthreads();
    #pragma unroll
    for (int i = 0; i < 32; i += 8)
        out[(ty + i) * 32 + tx] = (bf16)(tile[tx][ty + i] * scale);
}

// ---------------------------------------------------------------- fused (addpos+)LN+QKV (MFMA)
template <bool ADDPOS>
__global__ __launch_bounds__(256) void k_lnqkv(const float* __restrict__ xin,
                                               const float* __restrict__ pos,
                                               float* __restrict__ hout,
                                               const bf16* __restrict__ Wqt,
                                               const bf16* __restrict__ Wkt,
                                               const bf16* __restrict__ Wvt,
                                               bf16* __restrict__ qb,
                                               bf16* __restrict__ kb,
                                               bf16* __restrict__ vb) {
    __shared__ __attribute__((aligned(16))) bf16 Xs[64 * 264];
    int b = blockIdx.x, s0 = blockIdx.y * 64;
    int tid = threadIdx.x, w = tid >> 6, lane = tid & 63;
    size_t rowoff = ((size_t)(b * SS + s0 + w * 16)) * EE + lane * 4;
    const float* hb = xin + rowoff;
    float4 pv;
    if (ADDPOS) pv = *(const float4*)(pos + lane * 4);
    float4 xr[16];
    #pragma unroll
    for (int i = 0; i < 16; i++)
        xr[i] = *(const float4*)(hb + (size_t)i * EE);
    if (ADDPOS) {
        #pragma unroll
        for (int i = 0; i < 16; i++) {
            xr[i].x += pv.x; xr[i].y += pv.y; xr[i].z += pv.z; xr[i].w += pv.w;
            *(float4*)(hout + rowoff + (size_t)i * EE) = xr[i];
        }
    }
    #pragma unroll
    for (int i = 0; i < 16; i++) {
        float4 v4 = xr[i];
        float sum = v4.x + v4.y + v4.z + v4.w;
        #pragma unroll
        for (int m = 1; m <= 32; m <<= 1) sum += __shfl_xor(sum, m, 64);
        float mean = sum * (1.0f / EE);
        float dx = v4.x - mean, dy = v4.y - mean, dz = v4.z - mean, dw = v4.w - mean;
        float ss = dx * dx + dy * dy + dz * dz + dw * dw;
        #pragma unroll
        for (int m = 1; m <= 32; m <<= 1) ss += __shfl_xor(ss, m, 64);
        float rstd = rsqrtf(ss * (1.0f / EE) + LN_EPS);
        bf16x4 o4 = { (bf16)(dx * rstd), (bf16)(dy * rstd), (bf16)(dz * rstd), (bf16)(dw * rstd) };
        *(bf16x4*)&Xs[(w * 16 + i) * 264 + lane * 4] = o4;
    }
    __syncthreads();
    int col = lane & 15, quad = lane >> 4;
    #pragma unroll
    for (int h = 0; h < HH; h++) {
        bf16x8 a = *(const bf16x8*)&Xs[(w * 16 + col) * 264 + h * 32 + quad * 8];
        size_t base = ((size_t)((b * HH + h) * SS) + s0 + w * 16) * DHD;
        #pragma unroll
        for (int nt = 0; nt < 2; nt++) {
            int e = nt * 16 + col;
            bf16x8 bq  = *(const bf16x8*)(Wqt + (h * 32 + e) * 32 + quad * 8);
            bf16x8 bk2 = *(const bf16x8*)(Wkt + (h * 32 + e) * 32 + quad * 8);
            bf16x8 bv2 = *(const bf16x8*)(Wvt + (h * 32 + e) * 32 + quad * 8);
            f32x4 z = {0.f, 0.f, 0.f, 0.f};
            f32x4 cq = __builtin_amdgcn_mfma_f32_16x16x32_bf16(a, bq, z, 0, 0, 0);
            f32x4 ck = __builtin_amdgcn_mfma_f32_16x16x32_bf16(a, bk2, z, 0, 0, 0);
            f32x4 cv = __builtin_amdgcn_mfma_f32_16x16x32_bf16(a, bv2, z, 0, 0, 0);
            #pragma unroll
            for (int r = 0; r < 4; r++) {
                qb[base + (quad * 4 + r) * DHD + e] = (bf16)cq[r];
                kb[base + (quad * 4 + r) * DHD + e] = (bf16)ck[r];
            }
            bf16x4 vv = { (bf16)cv[0], (bf16)cv[1], (bf16)cv[2], (bf16)cv[3] };
            *(bf16x4*)&vb[(((size_t)(b * HH + h)) * DHD + e) * SS + s0 + w * 16 + quad * 4] = vv;
        }
    }
}

// ---------------------------------------------------------------- MFMA flash attention v3
#define ATT_LDK 40
#define ATT_LDV 264
#define ATT_LDP 36
__global__ __launch_bounds__(256) void k_attn(const bf16* __restrict__ Q,
                                              const bf16* __restrict__ K,
                                              const bf16* __restrict__ VT,
                                              bf16* __restrict__ O) {
    __shared__ __attribute__((aligned(16))) bf16 Ks[256 * ATT_LDK];
    __shared__ __attribute__((aligned(16))) bf16 Vs[32 * ATT_LDV];
    __shared__ __attribute__((aligned(16))) bf16 Ps[4][16 * ATT_LDP];
    int bh = blockIdx.x;
    int q0 = blockIdx.y * 128;
    int tid = threadIdx.x;
    int w = tid >> 6, lane = tid & 63;
    int col = lane & 15, quad = lane >> 4;
    bf16x8 aq[2];
    #pragma unroll
    for (int sub = 0; sub < 2; sub++)
        aq[sub] = *(const bf16x8*)(Q + ((size_t)(bh * SS + q0 + sub * 64 + w * 16 + col)) * DHD + quad * 8);
    float lr[2] = {0.f, 0.f};
    f32x4 oacc[2][2] = {};
    int ksr = tid >> 2, ksc = (tid & 3) * 8;   // K staging: 64 rows/iter x 32 d
    int vd  = tid >> 5, vso = (tid & 31) * 8;  // VT staging: 8 d-rows/pass x 256 s
    for (int ph = 0; ph < 2; ph++) {
        int t00 = ph * 256;
        __syncthreads();
        #pragma unroll
        for (int it = 0; it < 4; it++) {
            int rl = it * 64 + ksr;
            *(bf16x8*)&Ks[rl * ATT_LDK + ksc] =
                *(const bf16x8*)(K + ((size_t)(bh * SS + t00 + rl)) * DHD + ksc);
        }
        #pragma unroll
        for (int it = 0; it < 4; it++) {
            int d = it * 8 + vd;
            *(bf16x8*)&Vs[d * ATT_LDV + vso] =
                *(const bf16x8*)(VT + (((size_t)bh * DHD + d) * SS) + t00 + vso);
        }
        __syncthreads();
        #pragma unroll
        for (int i = 0; i < 8; i++) {
            bf16x8 bk[2], bv[2];
            #pragma unroll
            for (int nt = 0; nt < 2; nt++) {
                bk[nt] = *(const bf16x8*)&Ks[(i * 32 + nt * 16 + col) * ATT_LDK + quad * 8];
                bv[nt] = *(const bf16x8*)&Vs[(nt * 16 + col) * ATT_LDV + i * 32 + quad * 8];
            }
            #pragma unroll
            for (int sub = 0; sub < 2; sub++) {
                #pragma unroll
                for (int nt = 0; nt < 2; nt++) {
                    f32x4 z = {0.f, 0.f, 0.f, 0.f};
                    f32x4 st = __builtin_amdgcn_mfma_f32_16x16x32_bf16(bk[nt], aq[sub], z, 0, 0, 0);
                    bf16x4 p4;
                    #pragma unroll
                    for (int r = 0; r < 4; r++) {
                        float p = __expf(st[r]);
                        lr[sub] += p;
                        p4[r] = (bf16)p;
                    }
                    *(bf16x4*)&Ps[w][col * ATT_LDP + nt * 16 + quad * 4] = p4;
                }
                bf16x4 apl = *(const bf16x4*)&Ps[w][col * ATT_LDP + quad * 8];
                bf16x4 aph = *(const bf16x4*)&Ps[w][col * ATT_LDP + quad * 8 + 4];
                bf16x8 ap;
                ap[0] = apl[0]; ap[1] = apl[1]; ap[2] = apl[2]; ap[3] = apl[3];
                ap[4] = aph[0]; ap[5] = aph[1]; ap[6] = aph[2]; ap[7] = aph[3];
                #pragma unroll
                for (int nt = 0; nt < 2; nt++)
                    oacc[sub][nt] = __builtin_amdgcn_mfma_f32_16x16x32_bf16(ap, bv[nt], oacc[sub][nt], 0, 0, 0);
            }
        }
    }
    int b = bh >> 3, hh = bh & 7;
    #pragma unroll
    for (int sub = 0; sub < 2; sub++) {
        float ls = lr[sub];
        ls += __shfl_xor(ls, 16, 64);
        ls += __shfl_xor(ls, 32, 64);
        #pragma unroll
        for (int r = 0; r < 4; r++) {
            float lrow = __shfl(ls, quad * 4 + r, 64);
            float inv = 1.0f / lrow;
            int row = q0 + sub * 64 + w * 16 + quad * 4 + r;
            size_t ob = ((size_t)(b * SS + row)) * EE + hh * 32;
            O[ob + col]      = (bf16)(oacc[sub][0][r] * inv);
            O[ob + 16 + col] = (bf16)(oacc[sub][1][r] * inv);
        }
    }
}

// ---------------------------------------------------------------- FFN1 v2: fused res+LN prologue,
// A-frags hoisted once, W1 streamed via coalesced glds16, GELU epilogue.
// grid (FFD/128, BS/64): col-tile fastest so the 8 blocks sharing a row-tile
// dispatch together (L2-hot redundant LN reads). Tile 64x128, 4 waves 32x64.
__global__ __launch_bounds__(256) void k_gemm1n(const bf16* __restrict__ ob,
                                                const float* __restrict__ hb,
                                                const bf16* __restrict__ Bt,    // W1t [FFD][E]
                                                const float* __restrict__ bias, // [FFD]
                                                bf16* __restrict__ C) {         // [BS][FFD]
    __shared__ __attribute__((aligned(16))) bf16 As[64 * 264];
    __shared__ __attribute__((aligned(16))) bf16 Bs[128 * 32];
    int tid = threadIdx.x, w = tid >> 6, lane = tid & 63;
    int col = lane & 15, quad = lane >> 4;
    int col0 = blockIdx.x * 128, row0 = blockIdx.y * 64;
    // ---- prologue: res = ob + h; LN -> As. wave w: rows w*16 .. +15
    #pragma unroll
    for (int i = 0; i < 16; i++) {
        int r = w * 16 + i;
        float4 h4 = *(const float4*)(hb + (size_t)(row0 + r) * EE + lane * 4);
        bf16x4 o4 = *(const bf16x4*)(ob + (size_t)(row0 + r) * EE + lane * 4);
        float v0 = h4.x + (float)o4[0], v1 = h4.y + (float)o4[1];
        float v2 = h4.z + (float)o4[2], v3 = h4.w + (float)o4[3];
        float sum = v0 + v1 + v2 + v3;
        #pragma unroll
        for (int m = 1; m <= 32; m <<= 1) sum += __shfl_xor(sum, m, 64);
        float mean = sum * (1.0f / EE);
        float d0 = v0 - mean, d1 = v1 - mean, d2 = v2 - mean, d3 = v3 - mean;
        float sq = d0 * d0 + d1 * d1 + d2 * d2 + d3 * d3;
        #pragma unroll
        for (int m = 1; m <= 32; m <<= 1) sq += __shfl_xor(sq, m, 64);
        float rstd = rsqrtf(sq * (1.0f / EE) + LN_EPS);
        bf16x4 a4 = { (bf16)(d0 * rstd), (bf16)(d1 * rstd), (bf16)(d2 * rstd), (bf16)(d3 * rstd) };
        *(bf16x4*)&As[r * 264 + lane * 4] = a4;
    }
    __syncthreads();
    // ---- hoist A-frags for all 8 k-steps (As never re-read)
    int wrow = (w >> 1) * 32, wcol = (w & 1) * 64;
    bf16x8 af[2][8];
    #pragma unroll
    for (int mt = 0; mt < 2; mt++)
        #pragma unroll
        for (int s = 0; s < 8; s++)
            af[mt][s] = *(const bf16x8*)&As[(wrow + mt * 16 + col) * 264 + s * 32 + quad * 8];
    // ---- K-loop: stream W1 col-tile through LDS (coalesced glds16)
    int lrow = lane >> 2, lch = (lane & 3) * 8;
    const bf16* Bg = Bt + (size_t)(col0 + w * 32 + lrow) * EE + lch;
    bf16* Bsw = &Bs[(w * 32) * 32];
    f32x4 acc[2][4] = {};
    for (int k0 = 0; k0 < EE; k0 += 32) {
        glds16(Bg + k0, Bsw);
        glds16(Bg + 16 * EE + k0, Bsw + 16 * 32);
        __syncthreads();
        bf16x8 bf_[4];
        #pragma unroll
        for (int nt = 0; nt < 4; nt++)
            bf_[nt] = *(const bf16x8*)&Bs[(wcol + nt * 16 + col) * 32 + quad * 8];
        int s = k0 >> 5;
        #pragma unroll
        for (int mt = 0; mt < 2; mt++)
            #pragma unroll
            for (int nt = 0; nt < 4; nt++)
                acc[mt][nt] = __builtin_amdgcn_mfma_f32_16x16x32_bf16(bf_[nt], af[mt][s], acc[mt][nt], 0, 0, 0);
        __syncthreads();
    }
    // ---- epilogue: gelu(C + bias) -> bf16 packed
    #pragma unroll
    for (int mt = 0; mt < 2; mt++) {
        int row = row0 + wrow + mt * 16 + col;
        #pragma unroll
        for (int nt = 0; nt < 4; nt++) {
            int cc = col0 + wcol + nt * 16 + quad * 4;
            float4 b4 = *(const float4*)&bias[cc];
            bf16x4 ov;
            ov[0] = (bf16)gelu_f(acc[mt][nt][0] + b4.x);
            ov[1] = (bf16)gelu_f(acc[mt][nt][1] + b4.y);
            ov[2] = (bf16)gelu_f(acc[mt][nt][2] + b4.z);
            ov[3] = (bf16)gelu_f(acc[mt][nt][3] + b4.w);
            *(bf16x4*)&C[(size_t)row * FFD + cc] = ov;
        }
    }
}

// ---------------------------------------------------------------- FFN2: m97-style GEMM (R7)
__global__ __launch_bounds__(256) void k_gemm2(const bf16* __restrict__ A,
                                               const bf16* __restrict__ Bt,
                                               const float* __restrict__ bias,
                                               const bf16* __restrict__ ob,
                                               const float* __restrict__ hb,
                                               float* __restrict__ Cf) {
    __shared__ __attribute__((aligned(16))) bf16 As[128 * 32];
    __shared__ __attribute__((aligned(16))) bf16 Bs[64 * 32];
    int tid = threadIdx.x, w = tid >> 6, lane = tid & 63;
    int col = lane & 15, quad = lane >> 4;
    int row0 = blockIdx.x * 128, col0 = blockIdx.y * 64;
    int lrow = lane >> 2, lch = (lane & 3) * 8;
    const bf16* Ag = A  + (size_t)(row0 + w * 32 + lrow) * FFD + lch;
    const bf16* Bg = Bt + (size_t)(col0 + w * 16 + lrow) * FFD + lch;
    bf16* Asw = &As[(w * 32) * 32];
    bf16* Bsw = &Bs[(w * 16) * 32];
    f32x4 acc[2][4] = {};
    for (int k0 = 0; k0 < FFD; k0 += 32) {
        glds16(Ag + k0, Asw);
        glds16(Ag + 16 * FFD + k0, Asw + 16 * 32);
        glds16(Bg + k0, Bsw);
        __syncthreads();
        bf16x8 af[2], bf_[4];
        #pragma unroll
        for (int mt = 0; mt < 2; mt++)
            af[mt] = *(const bf16x8*)&As[(w * 32 + mt * 16 + col) * 32 + quad * 8];
        #pragma unroll
        for (int nt = 0; nt < 4; nt++)
            bf_[nt] = *(const bf16x8*)&Bs[(nt * 16 + col) * 32 + quad * 8];
        #pragma unroll
        for (int mt = 0; mt < 2; mt++)
            #pragma unroll
            for (int nt = 0; nt < 4; nt++)
                acc[mt][nt] = __builtin_amdgcn_mfma_f32_16x16x32_bf16(bf_[nt], af[mt], acc[mt][nt], 0, 0, 0);
        __syncthreads();
    }
    #pragma unroll
    for (int mt = 0; mt < 2; mt++) {
        int row = row0 + w * 32 + mt * 16 + col;
        #pragma unroll
        for (int nt = 0; nt < 4; nt++) {
            int cc = col0 + nt * 16 + quad * 4;
            float4 b4 = *(const float4*)&bias[cc];
            float4 h4 = *(const float4*)&hb[(size_t)row * EE + cc];
            bf16x4 o4 = *(const bf16x4*)&ob[(size_t)row * EE + cc];
            float4 out;
            out.x = acc[mt][nt][0] + b4.x + h4.x + (float)o4[0];
            out.y = acc[mt][nt][1] + b4.y + h4.y + (float)o4[1];
            out.z = acc[mt][nt][2] + b4.z + h4.z + (float)o4[2];
            out.w = acc[mt][nt][3] + b4.w + h4.w + (float)o4[3];
            *(float4*)&Cf[(size_t)row * EE + cc] = out;
        }
    }
}

// ---------------------------------------------------------------- launch
extern "C" void kernel_launch(void* const* d_in, const int* in_sizes, int n_in,
                              void* d_out, int out_size, void* d_ws, size_t ws_size,
                              hipStream_t stream) {
    (void)in_sizes; (void)n_in; (void)out_size; (void)ws_size;
    const float* x   = (const float*)d_in[0];
    const float* pos = (const float*)d_in[1];
    const float* Wq  = (const float*)d_in[2];
    const float* Wk  = (const float*)d_in[3];
    const float* Wv  = (const float*)d_in[4];
    const float* W1  = (const float*)d_in[5];
    const float* b1  = (const float*)d_in[6];
    const float* W2  = (const float*)d_in[7];
    const float* b2  = (const float*)d_in[8];

    float* ws = (float*)d_ws;
    size_t N = (size_t)NBSE;
    float* h  = ws;                          // [0 .. 16MB) f32 residual stream
    bf16* ob  = (bf16*)(ws + N);             // [16 .. 24MB) attention out, concat layout
    bf16* qb  = (bf16*)(ws + 2 * N);         // [32 .. 40MB)
    bf16* kb  = qb + N;                      // [40 .. 48MB)
    bf16* vb  = kb + N;                      // [48 .. 56MB) (VT layout [bh][d][s])
    bf16* ffb = (bf16*)(ws + 2 * N);         // [32 .. 64MB) overlays qb,kb,vb (dead by FFN1)
    bf16* W1t = (bf16*)(ws + 4 * N);         // [64MB ..)
    bf16* W2t = W1t + (size_t)LL * EE * FFD;
    bf16* Wqt = W2t + (size_t)LL * EE * FFD;
    bf16* Wkt = Wqt + (size_t)LL * HH * DHD * DHD;
    bf16* Wvt = Wkt + (size_t)LL * HH * DHD * DHD;

    k_cvt_t<<<dim3(FFD / 32, EE / 32, LL), 256, 0, stream>>>(W1, W1t, EE, FFD);
    k_cvt_t<<<dim3(EE / 32, FFD / 32, LL), 256, 0, stream>>>(W2, W2t, FFD, EE);
    k_cvt_qkv<<<dim3(LL * HH, 3), 256, 0, stream>>>(Wq, Wk, Wv, Wqt, Wkt, Wvt);
    for (int l = 0; l < LL; l++) {
        if (l == 0)
            k_lnqkv<true><<<dim3(BB, SS / 64), 256, 0, stream>>>(
                x, pos, h, Wqt, Wkt, Wvt, qb, kb, vb);
        else
            k_lnqkv<false><<<dim3(BB, SS / 64), 256, 0, stream>>>(
                h, nullptr, nullptr,
                Wqt + (size_t)l * HH * DHD * DHD, Wkt + (size_t)l * HH * DHD * DHD,
                Wvt + (size_t)l * HH * DHD * DHD, qb, kb, vb);
        k_attn<<<dim3(BB * HH, SS / 128), 256, 0, stream>>>(qb, kb, vb, ob);
        k_gemm1n<<<dim3(FFD / 128, BB * SS / 64), 256, 0, stream>>>(
            ob, h, W1t + (size_t)l * FFD * EE, b1 + (size_t)l * FFD, ffb);
        float* outp = (l == LL - 1) ? (float*)d_out : h;
        k_gemm2<<<dim3(BB * SS / 128, EE / 64), 256, 0, stream>>>(
            ffb, W2t + (size_t)l * EE * FFD, b2 + (size_t)l * EE, ob, h, outp);
    }
}

// Round 10
// 460.205 us; speedup vs baseline: 1.2821x; 1.1644x over previous
//
#include <hip/hip_runtime.h>
#include <math.h>

// Problem constants
#define BB   32
#define SS   512
#define EE   256
#define HH   8
#define LL   4
#define FFD  1024
#define DHD  32

constexpr float LN_EPS = 1e-5f;
constexpr int   NBSE   = BB * SS * EE;   // 4,194,304

typedef float  f32x4  __attribute__((ext_vector_type(4)));
typedef __bf16 bf16;
typedef __bf16 bf16x4 __attribute__((ext_vector_type(4)));
typedef __bf16 bf16x8 __attribute__((ext_vector_type(8)));

// async global->LDS, 16B per lane; LDS dest is wave-uniform base + lane*16B
__device__ __forceinline__ void glds16(const bf16* g, bf16* l) {
    __builtin_amdgcn_global_load_lds(
        (const __attribute__((address_space(1))) void*)g,
        (__attribute__((address_space(3))) void*)l,
        16, 0, 0);
}

// tanh-form GELU (|err| vs exact erf-GELU ~1e-3, safe within bf16 tolerance)
__device__ __forceinline__ float gelu_f(float x) {
    float u = x * x;
    float t = 1.5957691216057308f * x * (1.0f + 0.044715f * u);
    return x / (1.0f + __expf(-t));
}

// ---------------------------------------------------------------- weight prep
__global__ __launch_bounds__(256) void k_cvt_t(const float* __restrict__ in,
                                               bf16* __restrict__ out,
                                               int K, int N) {
    __shared__ float tile[32][33];
    in  += (size_t)blockIdx.z * K * N;
    out += (size_t)blockIdx.z * K * N;
    int n0 = blockIdx.x * 32, k0 = blockIdx.y * 32;
    int tx = threadIdx.x & 31, ty = threadIdx.x >> 5;   // 32 x 8
    #pragma unroll
    for (int i = 0; i < 32; i += 8)
        tile[ty + i][tx] = in[(size_t)(k0 + ty + i) * N + n0 + tx];
    __syncthreads();
    #pragma unroll
    for (int i = 0; i < 32; i += 8)
        out[(size_t)(n0 + ty + i) * K + k0 + tx] = (bf16)tile[tx][ty + i];
}

__global__ __launch_bounds__(256) void k_cvt_qkv(const float* __restrict__ Wq,
                                                 const float* __restrict__ Wk,
                                                 const float* __restrict__ Wv,
                                                 bf16* __restrict__ Wqt,
                                                 bf16* __restrict__ Wkt,
                                                 bf16* __restrict__ Wvt) {
    __shared__ float tile[32][33];
    int lh = blockIdx.x;            // l*H + h
    int z  = blockIdx.y;            // 0=q,1=k,2=v
    const float* in = (z == 0 ? Wq : z == 1 ? Wk : Wv) + (size_t)lh * 1024;
    bf16* out       = (z == 0 ? Wqt : z == 1 ? Wkt : Wvt) + (size_t)lh * 1024;
    float scale = (z == 0) ? 0.17677669529663687f : 1.0f;
    int tx = threadIdx.x & 31, ty = threadIdx.x >> 5;
    #pragma unroll
    for (int i = 0; i < 32; i += 8)
        tile[ty + i][tx] = in[(ty + i) * 32 + tx];
    __syncthreads();
    #pragma unroll
    for (int i = 0; i < 32; i += 8)
        out[(ty + i) * 32 + tx] = (bf16)(tile[tx][ty + i] * scale);
}

// ---------------------------------------------------------------- fused (addpos+)LN+QKV (MFMA)
template <bool ADDPOS>
__global__ __launch_bounds__(256) void k_lnqkv(const float* __restrict__ xin,
                                               const float* __restrict__ pos,
                                               float* __restrict__ hout,
                                               const bf16* __restrict__ Wqt,
                                               const bf16* __restrict__ Wkt,
                                               const bf16* __restrict__ Wvt,
                                               bf16* __restrict__ qb,
                                               bf16* __restrict__ kb,
                                               bf16* __restrict__ vb) {
    __shared__ __attribute__((aligned(16))) bf16 Xs[64 * 264];
    int b = blockIdx.x, s0 = blockIdx.y * 64;
    int tid = threadIdx.x, w = tid >> 6, lane = tid & 63;
    size_t rowoff = ((size_t)(b * SS + s0 + w * 16)) * EE + lane * 4;
    const float* hb = xin + rowoff;
    float4 pv;
    if (ADDPOS) pv = *(const float4*)(pos + lane * 4);
    float4 xr[16];
    #pragma unroll
    for (int i = 0; i < 16; i++)
        xr[i] = *(const float4*)(hb + (size_t)i * EE);
    if (ADDPOS) {
        #pragma unroll
        for (int i = 0; i < 16; i++) {
            xr[i].x += pv.x; xr[i].y += pv.y; xr[i].z += pv.z; xr[i].w += pv.w;
            *(float4*)(hout + rowoff + (size_t)i * EE) = xr[i];
        }
    }
    #pragma unroll
    for (int i = 0; i < 16; i++) {
        float4 v4 = xr[i];
        float sum = v4.x + v4.y + v4.z + v4.w;
        #pragma unroll
        for (int m = 1; m <= 32; m <<= 1) sum += __shfl_xor(sum, m, 64);
        float mean = sum * (1.0f / EE);
        float dx = v4.x - mean, dy = v4.y - mean, dz = v4.z - mean, dw = v4.w - mean;
        float ss = dx * dx + dy * dy + dz * dz + dw * dw;
        #pragma unroll
        for (int m = 1; m <= 32; m <<= 1) ss += __shfl_xor(ss, m, 64);
        float rstd = rsqrtf(ss * (1.0f / EE) + LN_EPS);
        bf16x4 o4 = { (bf16)(dx * rstd), (bf16)(dy * rstd), (bf16)(dz * rstd), (bf16)(dw * rstd) };
        *(bf16x4*)&Xs[(w * 16 + i) * 264 + lane * 4] = o4;
    }
    __syncthreads();
    int col = lane & 15, quad = lane >> 4;
    #pragma unroll
    for (int h = 0; h < HH; h++) {
        bf16x8 a = *(const bf16x8*)&Xs[(w * 16 + col) * 264 + h * 32 + quad * 8];
        size_t base = ((size_t)((b * HH + h) * SS) + s0 + w * 16) * DHD;
        #pragma unroll
        for (int nt = 0; nt < 2; nt++) {
            int e = nt * 16 + col;
            bf16x8 bq  = *(const bf16x8*)(Wqt + (h * 32 + e) * 32 + quad * 8);
            bf16x8 bk2 = *(const bf16x8*)(Wkt + (h * 32 + e) * 32 + quad * 8);
            bf16x8 bv2 = *(const bf16x8*)(Wvt + (h * 32 + e) * 32 + quad * 8);
            f32x4 z = {0.f, 0.f, 0.f, 0.f};
            f32x4 cq = __builtin_amdgcn_mfma_f32_16x16x32_bf16(a, bq, z, 0, 0, 0);
            f32x4 ck = __builtin_amdgcn_mfma_f32_16x16x32_bf16(a, bk2, z, 0, 0, 0);
            f32x4 cv = __builtin_amdgcn_mfma_f32_16x16x32_bf16(a, bv2, z, 0, 0, 0);
            #pragma unroll
            for (int r = 0; r < 4; r++) {
                qb[base + (quad * 4 + r) * DHD + e] = (bf16)cq[r];
                kb[base + (quad * 4 + r) * DHD + e] = (bf16)ck[r];
            }
            bf16x4 vv = { (bf16)cv[0], (bf16)cv[1], (bf16)cv[2], (bf16)cv[3] };
            *(bf16x4*)&vb[(((size_t)(b * HH + h)) * DHD + e) * SS + s0 + w * 16 + quad * 4] = vv;
        }
    }
}

// ---------------------------------------------------------------- MFMA flash attention v3
#define ATT_LDK 40
#define ATT_LDV 264
#define ATT_LDP 36
__global__ __launch_bounds__(256) void k_attn(const bf16* __restrict__ Q,
                                              const bf16* __restrict__ K,
                                              const bf16* __restrict__ VT,
                                              bf16* __restrict__ O) {
    __shared__ __attribute__((aligned(16))) bf16 Ks[256 * ATT_LDK];
    __shared__ __attribute__((aligned(16))) bf16 Vs[32 * ATT_LDV];
    __shared__ __attribute__((aligned(16))) bf16 Ps[4][16 * ATT_LDP];
    int bh = blockIdx.x;
    int q0 = blockIdx.y * 128;
    int tid = threadIdx.x;
    int w = tid >> 6, lane = tid & 63;
    int col = lane & 15, quad = lane >> 4;
    bf16x8 aq[2];
    #pragma unroll
    for (int sub = 0; sub < 2; sub++)
        aq[sub] = *(const bf16x8*)(Q + ((size_t)(bh * SS + q0 + sub * 64 + w * 16 + col)) * DHD + quad * 8);
    float lr[2] = {0.f, 0.f};
    f32x4 oacc[2][2] = {};
    int ksr = tid >> 2, ksc = (tid & 3) * 8;   // K staging: 64 rows/iter x 32 d
    int vd  = tid >> 5, vso = (tid & 31) * 8;  // VT staging: 8 d-rows/pass x 256 s
    for (int ph = 0; ph < 2; ph++) {
        int t00 = ph * 256;
        __syncthreads();
        #pragma unroll
        for (int it = 0; it < 4; it++) {
            int rl = it * 64 + ksr;
            *(bf16x8*)&Ks[rl * ATT_LDK + ksc] =
                *(const bf16x8*)(K + ((size_t)(bh * SS + t00 + rl)) * DHD + ksc);
        }
        #pragma unroll
        for (int it = 0; it < 4; it++) {
            int d = it * 8 + vd;
            *(bf16x8*)&Vs[d * ATT_LDV + vso] =
                *(const bf16x8*)(VT + (((size_t)bh * DHD + d) * SS) + t00 + vso);
        }
        __syncthreads();
        #pragma unroll
        for (int i = 0; i < 8; i++) {
            bf16x8 bk[2], bv[2];
            #pragma unroll
            for (int nt = 0; nt < 2; nt++) {
                bk[nt] = *(const bf16x8*)&Ks[(i * 32 + nt * 16 + col) * ATT_LDK + quad * 8];
                bv[nt] = *(const bf16x8*)&Vs[(nt * 16 + col) * ATT_LDV + i * 32 + quad * 8];
            }
            #pragma unroll
            for (int sub = 0; sub < 2; sub++) {
                #pragma unroll
                for (int nt = 0; nt < 2; nt++) {
                    f32x4 z = {0.f, 0.f, 0.f, 0.f};
                    f32x4 st = __builtin_amdgcn_mfma_f32_16x16x32_bf16(bk[nt], aq[sub], z, 0, 0, 0);
                    bf16x4 p4;
                    #pragma unroll
                    for (int r = 0; r < 4; r++) {
                        float p = __expf(st[r]);
                        lr[sub] += p;
                        p4[r] = (bf16)p;
                    }
                    *(bf16x4*)&Ps[w][col * ATT_LDP + nt * 16 + quad * 4] = p4;
                }
                bf16x4 apl = *(const bf16x4*)&Ps[w][col * ATT_LDP + quad * 8];
                bf16x4 aph = *(const bf16x4*)&Ps[w][col * ATT_LDP + quad * 8 + 4];
                bf16x8 ap;
                ap[0] = apl[0]; ap[1] = apl[1]; ap[2] = apl[2]; ap[3] = apl[3];
                ap[4] = aph[0]; ap[5] = aph[1]; ap[6] = aph[2]; ap[7] = aph[3];
                #pragma unroll
                for (int nt = 0; nt < 2; nt++)
                    oacc[sub][nt] = __builtin_amdgcn_mfma_f32_16x16x32_bf16(ap, bv[nt], oacc[sub][nt], 0, 0, 0);
            }
        }
    }
    int b = bh >> 3, hh = bh & 7;
    #pragma unroll
    for (int sub = 0; sub < 2; sub++) {
        float ls = lr[sub];
        ls += __shfl_xor(ls, 16, 64);
        ls += __shfl_xor(ls, 32, 64);
        #pragma unroll
        for (int r = 0; r < 4; r++) {
            float lrow = __shfl(ls, quad * 4 + r, 64);
            float inv = 1.0f / lrow;
            int row = q0 + sub * 64 + w * 16 + quad * 4 + r;
            size_t ob = ((size_t)(b * SS + row)) * EE + hh * 32;
            O[ob + col]      = (bf16)(oacc[sub][0][r] * inv);
            O[ob + 16 + col] = (bf16)(oacc[sub][1][r] * inv);
        }
    }
}

// ---------------------------------------------------------------- res + LN, wave per row
__global__ __launch_bounds__(256) void k_resln(const bf16* __restrict__ ob,
                                               const float* __restrict__ hb,
                                               bf16* __restrict__ rn) {
    int row  = blockIdx.x * 4 + (threadIdx.x >> 6);
    int lane = threadIdx.x & 63;
    float4 h4 = *(const float4*)(hb + (size_t)row * EE + lane * 4);
    bf16x4 o4 = *(const bf16x4*)(ob + (size_t)row * EE + lane * 4);
    float v0 = h4.x + (float)o4[0], v1 = h4.y + (float)o4[1];
    float v2 = h4.z + (float)o4[2], v3 = h4.w + (float)o4[3];
    float sum = v0 + v1 + v2 + v3;
    #pragma unroll
    for (int m = 1; m <= 32; m <<= 1) sum += __shfl_xor(sum, m, 64);
    float mean = sum * (1.0f / EE);
    float d0 = v0 - mean, d1 = v1 - mean, d2 = v2 - mean, d3 = v3 - mean;
    float sq = d0 * d0 + d1 * d1 + d2 * d2 + d3 * d3;
    #pragma unroll
    for (int m = 1; m <= 32; m <<= 1) sq += __shfl_xor(sq, m, 64);
    float rstd = rsqrtf(sq * (1.0f / EE) + LN_EPS);
    bf16x4 r4 = { (bf16)(d0 * rstd), (bf16)(d1 * rstd), (bf16)(d2 * rstd), (bf16)(d3 * rstd) };
    *(bf16x4*)(rn + (size_t)row * EE + lane * 4) = r4;
}

// ---------------------------------------------------------------- FFN1 v4: full-K A resident
// A=rnb [BS][256], tile 64x128, grid (BS/64, FFD/128) row-fastest (XCD co-location:
// bid%8 = rowtile%8, all 8 col-blocks of a row-tile share an XCD L2).
// A staged ONCE via contiguous glds16, A-frags hoisted; W1 double-buffered BK=64.
__global__ __launch_bounds__(256) void k_gemm1v(const bf16* __restrict__ A,
                                                const bf16* __restrict__ Bt,    // W1t [FFD][E]
                                                const float* __restrict__ bias, // [FFD]
                                                bf16* __restrict__ C) {         // [BS][FFD]
    __shared__ __attribute__((aligned(16))) bf16 As[8 * 2048];     // [s][64][32] 32 KB
    __shared__ __attribute__((aligned(16))) bf16 Bs[2][2 * 4096];  // [buf][kh][128][32] 16 KB ea
    int tid = threadIdx.x, w = tid >> 6, lane = tid & 63;
    int col = lane & 15, quad = lane >> 4;
    int wrow = (w >> 1) * 32, wcol = (w & 1) * 64;
    int row0 = blockIdx.x * 64, col0 = blockIdx.y * 128;
    int lrow = lane >> 2, lch = (lane & 3) * 8;
    // stage full-K A tile (contiguous 32 KB): wave w -> k-steps 2w, 2w+1
    #pragma unroll
    for (int j = 0; j < 2; j++) {
        int s = w * 2 + j;
        #pragma unroll
        for (int c = 0; c < 4; c++)
            glds16(A + (size_t)(row0 + c * 16 + lrow) * EE + s * 32 + lch,
                   &As[s * 2048 + c * 512]);
    }
    // stage B iter 0 -> buf 0: wave w -> chunks w*4..+3 (kh = ch>>3, rows (ch&7)*16)
    #pragma unroll
    for (int c = 0; c < 4; c++) {
        int ch = w * 4 + c, kh = ch >> 3, rb = (ch & 7) * 16;
        glds16(Bt + (size_t)(col0 + rb + lrow) * EE + kh * 32 + lch,
               &Bs[0][kh * 4096 + rb * 32]);
    }
    __syncthreads();
    bf16x8 af[2][8];
    #pragma unroll
    for (int mt = 0; mt < 2; mt++)
        #pragma unroll
        for (int s = 0; s < 8; s++)
            af[mt][s] = *(const bf16x8*)&As[s * 2048 + (wrow + mt * 16 + col) * 32 + quad * 8];
    f32x4 acc[2][4] = {};
    for (int it = 0; it < 4; it++) {
        if (it < 3) {
            int nb = (it + 1) & 1, k0 = (it + 1) * 64;
            #pragma unroll
            for (int c = 0; c < 4; c++) {
                int ch = w * 4 + c, kh = ch >> 3, rb = (ch & 7) * 16;
                glds16(Bt + (size_t)(col0 + rb + lrow) * EE + k0 + kh * 32 + lch,
                       &Bs[nb][kh * 4096 + rb * 32]);
            }
        }
        int bu = it & 1;
        #pragma unroll
        for (int kh = 0; kh < 2; kh++) {
            bf16x8 bf_[4];
            #pragma unroll
            for (int nt = 0; nt < 4; nt++)
                bf_[nt] = *(const bf16x8*)&Bs[bu][kh * 4096 + (wcol + nt * 16 + col) * 32 + quad * 8];
            int s = it * 2 + kh;
            #pragma unroll
            for (int mt = 0; mt < 2; mt++)
                #pragma unroll
                for (int nt = 0; nt < 4; nt++)
                    acc[mt][nt] = __builtin_amdgcn_mfma_f32_16x16x32_bf16(bf_[nt], af[mt][s], acc[mt][nt], 0, 0, 0);
        }
        __syncthreads();
    }
    #pragma unroll
    for (int mt = 0; mt < 2; mt++) {
        int row = row0 + wrow + mt * 16 + col;
        #pragma unroll
        for (int nt = 0; nt < 4; nt++) {
            int cc = col0 + wcol + nt * 16 + quad * 4;
            float4 b4 = *(const float4*)&bias[cc];
            bf16x4 ov;
            ov[0] = (bf16)gelu_f(acc[mt][nt][0] + b4.x);
            ov[1] = (bf16)gelu_f(acc[mt][nt][1] + b4.y);
            ov[2] = (bf16)gelu_f(acc[mt][nt][2] + b4.z);
            ov[3] = (bf16)gelu_f(acc[mt][nt][3] + b4.w);
            *(bf16x4*)&C[(size_t)row * FFD + cc] = ov;
        }
    }
}

// ---------------------------------------------------------------- FFN2 v2: BK=64 double-buffered
// tile 128x64, grid (BS/128, EE/64) row-fastest (co-located). 16 iters x 1 barrier.
__global__ __launch_bounds__(256) void k_gemm2v(const bf16* __restrict__ A,     // ffb [BS][FFD]
                                                const bf16* __restrict__ Bt,    // W2t [EE][FFD]
                                                const float* __restrict__ bias,
                                                const bf16* __restrict__ ob,
                                                const float* __restrict__ hb,
                                                float* __restrict__ Cf) {
    __shared__ __attribute__((aligned(16))) bf16 As[2][2 * 4096];  // [buf][kh][128][32]
    __shared__ __attribute__((aligned(16))) bf16 Bs[2][2 * 2048];  // [buf][kh][64][32]
    int tid = threadIdx.x, w = tid >> 6, lane = tid & 63;
    int col = lane & 15, quad = lane >> 4;
    int row0 = blockIdx.x * 128, col0 = blockIdx.y * 64;
    int lrow = lane >> 2, lch = (lane & 3) * 8;
    // stage iter 0 -> buf 0
    #pragma unroll
    for (int c = 0; c < 4; c++) {
        int ch = w * 4 + c, kh = ch >> 3, rb = (ch & 7) * 16;
        glds16(A + (size_t)(row0 + rb + lrow) * FFD + kh * 32 + lch,
               &As[0][kh * 4096 + rb * 32]);
    }
    #pragma unroll
    for (int c = 0; c < 2; c++) {
        int ch = w * 2 + c, kh = ch >> 2, rb = (ch & 3) * 16;
        glds16(Bt + (size_t)(col0 + rb + lrow) * FFD + kh * 32 + lch,
               &Bs[0][kh * 2048 + rb * 32]);
    }
    __syncthreads();
    f32x4 acc[2][4] = {};
    for (int it = 0; it < 16; it++) {
        if (it < 15) {
            int nb = (it + 1) & 1, k0 = (it + 1) * 64;
            #pragma unroll
            for (int c = 0; c < 4; c++) {
                int ch = w * 4 + c, kh = ch >> 3, rb = (ch & 7) * 16;
                glds16(A + (size_t)(row0 + rb + lrow) * FFD + k0 + kh * 32 + lch,
                       &As[nb][kh * 4096 + rb * 32]);
            }
            #pragma unroll
            for (int c = 0; c < 2; c++) {
                int ch = w * 2 + c, kh = ch >> 2, rb = (ch & 3) * 16;
                glds16(Bt + (size_t)(col0 + rb + lrow) * FFD + k0 + kh * 32 + lch,
                       &Bs[nb][kh * 2048 + rb * 32]);
            }
        }
        int bu = it & 1;
        #pragma unroll
        for (int kh = 0; kh < 2; kh++) {
            bf16x8 af[2], bf_[4];
            #pragma unroll
            for (int mt = 0; mt < 2; mt++)
                af[mt] = *(const bf16x8*)&As[bu][kh * 4096 + (w * 32 + mt * 16 + col) * 32 + quad * 8];
            #pragma unroll
            for (int nt = 0; nt < 4; nt++)
                bf_[nt] = *(const bf16x8*)&Bs[bu][kh * 2048 + (nt * 16 + col) * 32 + quad * 8];
            #pragma unroll
            for (int mt = 0; mt < 2; mt++)
                #pragma unroll
                for (int nt = 0; nt < 4; nt++)
                    acc[mt][nt] = __builtin_amdgcn_mfma_f32_16x16x32_bf16(bf_[nt], af[mt], acc[mt][nt], 0, 0, 0);
        }
        __syncthreads();
    }
    #pragma unroll
    for (int mt = 0; mt < 2; mt++) {
        int row = row0 + w * 32 + mt * 16 + col;
        #pragma unroll
        for (int nt = 0; nt < 4; nt++) {
            int cc = col0 + nt * 16 + quad * 4;
            float4 b4 = *(const float4*)&bias[cc];
            float4 h4 = *(const float4*)&hb[(size_t)row * EE + cc];
            bf16x4 o4 = *(const bf16x4*)&ob[(size_t)row * EE + cc];
            float4 out;
            out.x = acc[mt][nt][0] + b4.x + h4.x + (float)o4[0];
            out.y = acc[mt][nt][1] + b4.y + h4.y + (float)o4[1];
            out.z = acc[mt][nt][2] + b4.z + h4.z + (float)o4[2];
            out.w = acc[mt][nt][3] + b4.w + h4.w + (float)o4[3];
            *(float4*)&Cf[(size_t)row * EE + cc] = out;
        }
    }
}

// ---------------------------------------------------------------- launch
extern "C" void kernel_launch(void* const* d_in, const int* in_sizes, int n_in,
                              void* d_out, int out_size, void* d_ws, size_t ws_size,
                              hipStream_t stream) {
    (void)in_sizes; (void)n_in; (void)out_size; (void)ws_size;
    const float* x   = (const float*)d_in[0];
    const float* pos = (const float*)d_in[1];
    const float* Wq  = (const float*)d_in[2];
    const float* Wk  = (const float*)d_in[3];
    const float* Wv  = (const float*)d_in[4];
    const float* W1  = (const float*)d_in[5];
    const float* b1  = (const float*)d_in[6];
    const float* W2  = (const float*)d_in[7];
    const float* b2  = (const float*)d_in[8];

    float* ws = (float*)d_ws;
    size_t N = (size_t)NBSE;
    float* h  = ws;                          // [0 .. 16MB) f32 residual stream
    bf16* ob  = (bf16*)(ws + N);             // [16 .. 24MB) attention out, concat layout
    bf16* rnb = (bf16*)(ws + N) + N;         // [24 .. 32MB) LN(res)
    bf16* qb  = (bf16*)(ws + 2 * N);         // [32 .. 40MB)
    bf16* kb  = qb + N;                      // [40 .. 48MB)
    bf16* vb  = kb + N;                      // [48 .. 56MB) (VT layout [bh][d][s])
    bf16* ffb = (bf16*)(ws + 2 * N);         // [32 .. 64MB) overlays qb,kb,vb (dead by FFN1)
    bf16* W1t = (bf16*)(ws + 4 * N);         // [64MB ..)
    bf16* W2t = W1t + (size_t)LL * EE * FFD;
    bf16* Wqt = W2t + (size_t)LL * EE * FFD;
    bf16* Wkt = Wqt + (size_t)LL * HH * DHD * DHD;
    bf16* Wvt = Wkt + (size_t)LL * HH * DHD * DHD;

    k_cvt_t<<<dim3(FFD / 32, EE / 32, LL), 256, 0, stream>>>(W1, W1t, EE, FFD);
    k_cvt_t<<<dim3(EE / 32, FFD / 32, LL), 256, 0, stream>>>(W2, W2t, FFD, EE);
    k_cvt_qkv<<<dim3(LL * HH, 3), 256, 0, stream>>>(Wq, Wk, Wv, Wqt, Wkt, Wvt);
    for (int l = 0; l < LL; l++) {
        if (l == 0)
            k_lnqkv<true><<<dim3(BB, SS / 64), 256, 0, stream>>>(
                x, pos, h, Wqt, Wkt, Wvt, qb, kb, vb);
        else
            k_lnqkv<false><<<dim3(BB, SS / 64), 256, 0, stream>>>(
                h, nullptr, nullptr,
                Wqt + (size_t)l * HH * DHD * DHD, Wkt + (size_t)l * HH * DHD * DHD,
                Wvt + (size_t)l * HH * DHD * DHD, qb, kb, vb);
        k_attn<<<dim3(BB * HH, SS / 128), 256, 0, stream>>>(qb, kb, vb, ob);
        k_resln<<<BB * SS / 4, 256, 0, stream>>>(ob, h, rnb);
        k_gemm1v<<<dim3(BB * SS / 64, FFD / 128), 256, 0, stream>>>(
            rnb, W1t + (size_t)l * FFD * EE, b1 + (size_t)l * FFD, ffb);
        float* outp = (l == LL - 1) ? (float*)d_out : h;
        k_gemm2v<<<dim3(BB * SS / 128, EE / 64), 256, 0, stream>>>(
            ffb, W2t + (size_t)l * EE * FFD, b2 + (size_t)l * EE, ob, h, outp);
    }
}